// Round 2
// baseline (201.354 us; speedup 1.0000x reference)
//
#include <hip/hip_runtime.h>
#include <math.h>

#define D_MODEL 1024
#define NUM_EXPERTS 8
#define TOP_K 2
#define TOKENS_PER_WAVE 4
#define WAVES_PER_BLOCK 4
#define TOKENS_PER_BLOCK (TOKENS_PER_WAVE * WAVES_PER_BLOCK)

// block=256: 4 waves x 4 tokens each. W (32KB) staged in LDS once per block;
// each wave amortizes one LDS W-read across 4 tokens -> LDS traffic ~256MB
// total (~4us @69TB/s), safely under the 128MiB x-stream HBM floor (~21us).
__global__ __launch_bounds__(256) void gating_kernel(
    const float* __restrict__ x, const float* __restrict__ W,
    const float* __restrict__ b, float* __restrict__ out_w,
    float* __restrict__ out_idx, int n_tokens)
{
    __shared__ float Wlds[NUM_EXPERTS * D_MODEL];  // 32 KB

    // Stage W: 8192 floats = 2048 float4, 256 threads -> 8 float4 each.
    {
        const float4* Wg = (const float4*)W;
        float4* Ws = (float4*)Wlds;
        const int tid = threadIdx.x;
#pragma unroll
        for (int i = 0; i < (NUM_EXPERTS * D_MODEL / 4) / 256; ++i)
            Ws[tid + i * 256] = Wg[tid + i * 256];
    }
    __syncthreads();

    const int wave = threadIdx.x >> 6;
    const int lane = threadIdx.x & 63;
    const int token0 = (blockIdx.x * WAVES_PER_BLOCK + wave) * TOKENS_PER_WAVE;
    if (token0 >= n_tokens) return;

    float acc[TOKENS_PER_WAVE][NUM_EXPERTS];
#pragma unroll
    for (int t = 0; t < TOKENS_PER_WAVE; ++t)
#pragma unroll
        for (int e = 0; e < NUM_EXPERTS; ++e) acc[t][e] = 0.f;

    // Main loop: lane covers d = j*256 + lane*4 .. +4 (coalesced float4).
#pragma unroll
    for (int j = 0; j < D_MODEL / 256; ++j) {
        float4 xv[TOKENS_PER_WAVE];
#pragma unroll
        for (int t = 0; t < TOKENS_PER_WAVE; ++t)
            xv[t] = *(const float4*)(x + (size_t)(token0 + t) * D_MODEL + j * 256 + lane * 4);
#pragma unroll
        for (int e = 0; e < NUM_EXPERTS; ++e) {
            float4 wv = *(const float4*)(Wlds + e * D_MODEL + j * 256 + lane * 4);
#pragma unroll
            for (int t = 0; t < TOKENS_PER_WAVE; ++t) {
                acc[t][e] += xv[t].x * wv.x + xv[t].y * wv.y +
                             xv[t].z * wv.z + xv[t].w * wv.w;
            }
        }
    }

    // Butterfly reduce each of the 32 partial sums across all 64 lanes.
#pragma unroll
    for (int t = 0; t < TOKENS_PER_WAVE; ++t)
#pragma unroll
        for (int e = 0; e < NUM_EXPERTS; ++e) {
            float v = acc[t][e];
#pragma unroll
            for (int s = 32; s >= 1; s >>= 1) v += __shfl_xor(v, s, 64);
            acc[t][e] = v;
        }

    // Epilogue (wave-uniform redundant compute; writes predicated on lane==t).
#pragma unroll
    for (int t = 0; t < TOKENS_PER_WAVE; ++t) {
        float v0 = -INFINITY, v1 = -INFINITY;
        int i0 = 0, i1 = 0;
#pragma unroll
        for (int e = 0; e < NUM_EXPERTS; ++e) {
            float v = acc[t][e] + b[e];
            // strict > keeps lowest index on ties, matching jax.lax.top_k
            if (v > v0) { v1 = v0; i1 = i0; v0 = v; i0 = e; }
            else if (v > v1) { v1 = v; i1 = e; }
        }
        float e1 = expf(v1 - v0);
        float w0 = 1.f / (1.f + e1);
        float w1 = e1 * w0;
        if (lane == t) {
            float wout[NUM_EXPERTS];
#pragma unroll
            for (int e = 0; e < NUM_EXPERTS; ++e)
                wout[e] = (e == i0) ? w0 : ((e == i1) ? w1 : 0.f);
            float4* dst = (float4*)(out_w + (size_t)(token0 + t) * NUM_EXPERTS);
            dst[0] = make_float4(wout[0], wout[1], wout[2], wout[3]);
            dst[1] = make_float4(wout[4], wout[5], wout[6], wout[7]);
            float2* di = (float2*)(out_idx + (size_t)(token0 + t) * TOP_K);
            *di = make_float2((float)i0, (float)i1);
        }
    }
}

extern "C" void kernel_launch(void* const* d_in, const int* in_sizes, int n_in,
                              void* d_out, int out_size, void* d_ws, size_t ws_size,
                              hipStream_t stream) {
    const float* x = (const float*)d_in[0];
    const float* W = (const float*)d_in[1];
    const float* b = (const float*)d_in[2];
    float* out = (float*)d_out;

    const int n_tokens = in_sizes[0] / D_MODEL;              // 32768
    float* out_w   = out;                                    // [n_tokens, 8]
    float* out_idx = out + (size_t)n_tokens * NUM_EXPERTS;   // [n_tokens, 2] as float

    const int grid = (n_tokens + TOKENS_PER_BLOCK - 1) / TOKENS_PER_BLOCK;  // 2048
    gating_kernel<<<grid, 256, 0, stream>>>(x, W, b, out_w, out_idx, n_tokens);
}

// Round 4
// 185.538 us; speedup vs baseline: 1.0852x; 1.0852x over previous
//
#include <hip/hip_runtime.h>
#include <math.h>

#define D_MODEL 1024
#define NUM_EXPERTS 8
#define TOP_K 2
#define LANES_PER_TOKEN 8                          // L: 8 lanes cooperate on one token
#define TOKENS_PER_WAVE 8                          // T = 64/L
#define WAVES_PER_BLOCK 4
#define TOKENS_PER_BLOCK (TOKENS_PER_WAVE * WAVES_PER_BLOCK)  // 32

typedef float f4 __attribute__((ext_vector_type(4)));

// Layout: lane = g*8 + l. Group g owns token (block*32 + wave*8 + g); lane l
// covers d = l*4 + k*32 (k=0..31). Reduction = 3 butterfly steps within the
// 8-lane group (vs 6 over 64 lanes). W in LDS: per ds_read_b128 the 8 groups
// broadcast the same address (free), the 8 l-lanes read 128B contiguous ->
// conflict-free. x: 8 float4 nontemporal loads in flight per lane per chunk.
__global__ __launch_bounds__(256) void gating_kernel(
    const float* __restrict__ x, const float* __restrict__ W,
    const float* __restrict__ b, float* __restrict__ out_w,
    float* __restrict__ out_idx, int n_tokens)
{
    __shared__ float Wlds[NUM_EXPERTS * D_MODEL];  // 32 KB -> 5 blocks/CU max

    {   // stage W: 2048 float4 across 256 threads
        const f4* Wg = (const f4*)W;
        f4* Ws = (f4*)Wlds;
        const int tid = threadIdx.x;
#pragma unroll
        for (int i = 0; i < (NUM_EXPERTS * D_MODEL / 4) / 256; ++i)
            Ws[tid + i * 256] = Wg[tid + i * 256];
    }
    __syncthreads();

    const int wave = threadIdx.x >> 6;
    const int lane = threadIdx.x & 63;
    const int g = lane >> 3;
    const int l = lane & 7;
    const int token = blockIdx.x * TOKENS_PER_BLOCK + wave * TOKENS_PER_WAVE + g;
    if (token >= n_tokens) return;

    const f4* xg = (const f4*)x + (size_t)token * (D_MODEL / 4) + l;  // +k*8 per chunk
    const f4* Wl = (const f4*)Wlds + l;                               // +e*256 + k*8

    float acc[NUM_EXPERTS];
#pragma unroll
    for (int e = 0; e < NUM_EXPERTS; ++e) acc[e] = 0.f;

#pragma unroll
    for (int c = 0; c < 4; ++c) {
        f4 xa[8];
#pragma unroll
        for (int kk = 0; kk < 8; ++kk)
            xa[kk] = __builtin_nontemporal_load(xg + (c * 8 + kk) * 8);
#pragma unroll
        for (int e = 0; e < NUM_EXPERTS; ++e) {
            float s = acc[e];
#pragma unroll
            for (int kk = 0; kk < 8; ++kk) {
                const f4 wv = Wl[e * 256 + (c * 8 + kk) * 8];
                s += xa[kk].x * wv.x + xa[kk].y * wv.y +
                     xa[kk].z * wv.z + xa[kk].w * wv.w;
            }
            acc[e] = s;
        }
    }

    // Reduce across the 8 lanes of the group: 3 butterfly steps per expert.
#pragma unroll
    for (int e = 0; e < NUM_EXPERTS; ++e) {
        float v = acc[e];
        v += __shfl_xor(v, 1, 64);
        v += __shfl_xor(v, 2, 64);
        v += __shfl_xor(v, 4, 64);
        acc[e] = v + b[e];
    }

    // Every lane of the group holds the full logits; compute top-2 + softmax.
    float v0 = -INFINITY, v1 = -INFINITY;
    int i0 = 0, i1 = 0;
#pragma unroll
    for (int e = 0; e < NUM_EXPERTS; ++e) {
        float v = acc[e];
        // strict > keeps lowest index on ties, matching jax.lax.top_k
        if (v > v0) { v1 = v0; i1 = i0; v0 = v; i0 = e; }
        else if (v > v1) { v1 = v; i1 = e; }
    }
    const float e1 = expf(v1 - v0);
    const float w0 = 1.f / (1.f + e1);
    const float w1 = e1 * w0;

    // Writes spread over 3 lanes of each group; weight stores coalesce to
    // 256B-contiguous runs per wave.
    if (l < 2) {
        const int base = l * 4;
        f4 v4;
        v4.x = (base + 0 == i0) ? w0 : ((base + 0 == i1) ? w1 : 0.f);
        v4.y = (base + 1 == i0) ? w0 : ((base + 1 == i1) ? w1 : 0.f);
        v4.z = (base + 2 == i0) ? w0 : ((base + 2 == i1) ? w1 : 0.f);
        v4.w = (base + 3 == i0) ? w0 : ((base + 3 == i1) ? w1 : 0.f);
        ((f4*)(out_w + (size_t)token * NUM_EXPERTS))[l] = v4;
    } else if (l == 2) {
        *(float2*)(out_idx + (size_t)token * TOP_K) =
            make_float2((float)i0, (float)i1);
    }
}

extern "C" void kernel_launch(void* const* d_in, const int* in_sizes, int n_in,
                              void* d_out, int out_size, void* d_ws, size_t ws_size,
                              hipStream_t stream) {
    const float* x = (const float*)d_in[0];
    const float* W = (const float*)d_in[1];
    const float* b = (const float*)d_in[2];
    float* out = (float*)d_out;

    const int n_tokens = in_sizes[0] / D_MODEL;              // 32768
    float* out_w   = out;                                    // [n_tokens, 8]
    float* out_idx = out + (size_t)n_tokens * NUM_EXPERTS;   // [n_tokens, 2] as float

    const int grid = (n_tokens + TOKENS_PER_BLOCK - 1) / TOKENS_PER_BLOCK;  // 1024
    gating_kernel<<<grid, 256, 0, stream>>>(x, W, b, out_w, out_idx, n_tokens);
}